// Round 14
// baseline (240.278 us; speedup 1.0000x reference)
//
#include <hip/hip_runtime.h>
#include <hip/hip_bf16.h>

#define B_ 4
#define S_ 1024
#define D_ 1024
#define H_ 16
#define HD_ 64
#define M_ (B_*S_)
#define NT_ (S_/64)   // 16 k/v tiles

typedef __attribute__((ext_vector_type(8))) short bf16x8;
typedef __attribute__((ext_vector_type(8))) unsigned short u16x8;
typedef __attribute__((ext_vector_type(4))) float f32x4;

typedef __attribute__((address_space(1))) const unsigned int g_uint;
typedef __attribute__((address_space(3))) unsigned int l_uint;

__device__ __forceinline__ unsigned short f2bf(float f) {
  unsigned int x = __builtin_bit_cast(unsigned int, f);
  unsigned int r = (x + 0x7fffu + ((x >> 16) & 1u)) >> 16;
  return (unsigned short)r;
}
__device__ __forceinline__ float bf2f(unsigned short u) {
  unsigned int x = ((unsigned int)u) << 16;
  return __builtin_bit_cast(float, x);
}
__device__ __forceinline__ unsigned int cvtpk(float lo, float hi) {
  unsigned int r;
  asm("v_cvt_pk_bf16_f32 %0, %1, %2" : "=v"(r) : "v"(lo), "v"(hi));
  return r;
}
__device__ __forceinline__ void load_lds16(const ushort* g, ushort* l) {
  __builtin_amdgcn_global_load_lds((g_uint*)g, (l_uint*)l, 16, 0, 0);
}

// ---------------- W -> W^T bf16 (weights only; q/k/v cvt fused into gemm_qkv) ----
__global__ void trW(const float* __restrict__ Wq, const float* __restrict__ Wk,
                    const float* __restrict__ Wv, const float* __restrict__ Wo,
                    ushort* __restrict__ q, ushort* __restrict__ k,
                    ushort* __restrict__ v, ushort* __restrict__ o) {
  const float* W; ushort* WT;
  switch (blockIdx.z) {
    case 0: W = Wq; WT = q; break;
    case 1: W = Wk; WT = k; break;
    case 2: W = Wv; WT = v; break;
    default: W = Wo; WT = o; break;
  }
  __shared__ float tile[32][33];
  int tx = threadIdx.x & 31, ty = threadIdx.x >> 5;
  int bx = blockIdx.x * 32, by = blockIdx.y * 32;
  for (int r = 0; r < 32; r += 8)
    tile[ty + r][tx] = W[(size_t)(by + ty + r) * D_ + bx + tx];
  __syncthreads();
  for (int r = 0; r < 32; r += 8)
    WT[(size_t)(bx + ty + r) * D_ + by + tx] = f2bf(tile[tx][ty + r]);
}

// ---------------- bf16 MFMA GEMM: C[BM,BN] = A[M,K]*Bt[N,K]^T + bias ----------------
// AFP32: A is fp32 in global; staged via reg (float4 x2 -> cvt_pk -> ds_write_b128)
// into the SAME linear LDS layout global_load_lds produces (source swizzle sc8).
template <int BF16OUT, int BM, int BN, int AFP32>
__device__ __forceinline__ void gemm_body(const void* __restrict__ Ap,
                                          const ushort* __restrict__ Bt,
                                          const float* __restrict__ bias,
                                          void* __restrict__ Cp,
                                          int bm, int bn, int N, int K) {
  __shared__ ushort Al[BM * 64];
  __shared__ ushort Bl[BN * 64];
  constexpr int MF = BM / 32;   // a-frags / acc rows per wave
  constexpr int NF = BN / 32;   // b-frags / acc cols per wave
  const int tid = threadIdx.x;
  const int wave = tid >> 6, lane = tid & 63;
  const int r0 = lane & 15, kq = lane >> 4;
  const int wr = wave >> 1, wc = wave & 1;
  const int sl = lane >> 3;
  const int sc8 = ((lane & 7) ^ sl) * 8;   // swizzled source col (elements)
  f32x4 zero = {0.f, 0.f, 0.f, 0.f};
  f32x4 acc[MF][NF];
#pragma unroll
  for (int m = 0; m < MF; ++m)
#pragma unroll
    for (int n = 0; n < NF; ++n) acc[m][n] = zero;

  for (int kt = 0; kt < K; kt += 64) {
    __syncthreads();
    if (AFP32) {
      const float* A = (const float*)Ap;
#pragma unroll
      for (int i = 0; i < MF; ++i) {
        int c = wave * MF + i;
        const float* src = &A[(size_t)(bm + c * 8 + sl) * K + kt + sc8];
        float4 f0 = *(const float4*)src;
        float4 f1 = *(const float4*)(src + 4);
        uint4 pk;
        pk.x = cvtpk(f0.x, f0.y);
        pk.y = cvtpk(f0.z, f0.w);
        pk.z = cvtpk(f1.x, f1.y);
        pk.w = cvtpk(f1.z, f1.w);
        *(uint4*)&Al[c * 512 + lane * 8] = pk;   // linear dest = gload_lds layout
      }
    } else {
      const ushort* A = (const ushort*)Ap;
#pragma unroll
      for (int i = 0; i < MF; ++i) {
        int c = wave * MF + i;
        load_lds16(A + (size_t)(bm + c * 8 + sl) * K + kt + sc8, &Al[c * 512]);
      }
    }
#pragma unroll
    for (int i = 0; i < NF; ++i) {
      int c = wave * NF + i;
      load_lds16(Bt + (size_t)(bn + c * 8 + sl) * K + kt + sc8, &Bl[c * 512]);
    }
    __syncthreads();
#pragma unroll
    for (int kk = 0; kk < 2; ++kk) {
      bf16x8 a[MF], b[NF];
#pragma unroll
      for (int m = 0; m < MF; ++m)
        a[m] = *(const bf16x8*)&Al[(wr * (BM / 2) + m * 16 + r0) * 64 + (((kk * 4 + kq) ^ (r0 & 7)) * 8)];
#pragma unroll
      for (int n = 0; n < NF; ++n)
        b[n] = *(const bf16x8*)&Bl[(wc * (BN / 2) + n * 16 + r0) * 64 + (((kk * 4 + kq) ^ (r0 & 7)) * 8)];
#pragma unroll
      for (int m = 0; m < MF; ++m)
#pragma unroll
        for (int n = 0; n < NF; ++n)
          acc[m][n] = __builtin_amdgcn_mfma_f32_16x16x32_bf16(a[m], b[n], acc[m][n], 0, 0, 0);
    }
  }

#pragma unroll
  for (int m = 0; m < MF; ++m) {
#pragma unroll
    for (int n = 0; n < NF; ++n) {
      int col = bn + wc * (BN / 2) + n * 16 + r0;
      float bv = bias[col];
#pragma unroll
      for (int j = 0; j < 4; ++j) {
        int row = bm + wr * (BM / 2) + m * 16 + kq * 4 + j;
        float v = acc[m][n][j] + bv;
        if (BF16OUT) ((ushort*)Cp)[(size_t)row * N + col] = f2bf(v);
        else         ((float*)Cp)[(size_t)row * N + col] = v;
      }
    }
  }
}

__global__ __launch_bounds__(256) void gemm_qkv(const float* __restrict__ qa,
                                                const float* __restrict__ ka,
                                                const float* __restrict__ va,
                                                const ushort* __restrict__ WqT,
                                                const ushort* __restrict__ WkT,
                                                const ushort* __restrict__ WvT,
                                                const float* __restrict__ bq,
                                                const float* __restrict__ bk,
                                                const float* __restrict__ bv,
                                                ushort* __restrict__ Qo,
                                                ushort* __restrict__ Ko,
                                                ushort* __restrict__ Vo) {
  const float* A; const ushort* Bt; const float* bias; ushort* C;
  switch (blockIdx.z) {
    case 0: A = qa; Bt = WqT; bias = bq; C = Qo; break;
    case 1: A = ka; Bt = WkT; bias = bk; C = Ko; break;
    default: A = va; Bt = WvT; bias = bv; C = Vo; break;
  }
  gemm_body<1, 64, 128, 1>(A, Bt, bias, C, blockIdx.x * 64, blockIdx.y * 128, D_, D_);
}

__global__ __launch_bounds__(256) void gemm_out(const ushort* __restrict__ A,
                                                const ushort* __restrict__ Bt,
                                                const float* __restrict__ bias,
                                                float* __restrict__ C) {
  gemm_body<0, 64, 64, 0>(A, Bt, bias, C, blockIdx.x * 64, blockIdx.y * 64, D_, D_);
}

// ---------------- fused attention, PAIRED q-tiles (qtA=15-p heavy, qtB=p light) ----
// grid 512: id&63 = (b,h) -> XCD-local K/V panel; p = id>>6 (heavy pairs first).
__global__ __launch_bounds__(256) void attn_fused(const ushort* __restrict__ Qb,
                                                  const ushort* __restrict__ Kb,
                                                  const ushort* __restrict__ Vb,
                                                  float* __restrict__ wout,
                                                  ushort* __restrict__ ctx) {
  const int id = blockIdx.x;
  const int bh = id & 63;
  const int b = bh >> 4, h = bh & 15;
  const int p = id >> 6;
  const int qtA = NT_ - 1 - p;   // 8..15
  const int qtB = p;             // 0..7  (qtB < qtA always)
  const int tid = threadIdx.x, wave = tid >> 6, lane = tid & 63;
  const int r0 = lane & 15, kq = lane >> 4;
  const int sl = lane >> 3;
  const int sc8 = ((lane & 7) ^ sl) * 8;
  __shared__ ushort Kt[2][64 * 64];   // dbuf, both-sides swizzle slot^=(row&7)
  __shared__ ushort Vt[2][64 * 64];   // dbuf, V^T [d][k], col^=(d&7)<<3
  __shared__ ushort Wl[4][16 * 64];   // per-wave P tile, 8B-slot swizzle
  const size_t bh_off = ((size_t)(b * S_)) * D_ + (size_t)h * 64;
  float* wbase = wout + (size_t)bh * S_ * S_;
  const float KSC = 0.18033688011f;   // 0.125 * log2(e)

  const ushort* QgA = Qb + bh_off + (size_t)(qtA * 64 + wave * 16 + r0) * D_ + kq * 8;
  bf16x8 qa0A = *(const bf16x8*)QgA;
  bf16x8 qa1A = *(const bf16x8*)(QgA + 32);
  const ushort* QgB = Qb + bh_off + (size_t)(qtB * 64 + wave * 16 + r0) * D_ + kq * 8;
  bf16x8 qa0B = *(const bf16x8*)QgB;
  bf16x8 qa1B = *(const bf16x8*)(QgB + 32);
  const int qgA = qtA * 64 + wave * 16 + r0;
  const int qgB = qtB * 64 + wave * 16 + r0;

  auto stage_K = [&](int buf, int vb) {
    const ushort* Kg = Kb + bh_off + (size_t)(vb * 64) * D_;
#pragma unroll
    for (int i = 0; i < 2; ++i) {
      int c = wave * 2 + i;
      load_lds16(Kg + (size_t)(c * 8 + sl) * D_ + sc8, &Kt[buf][c * 512]);
    }
  };
  uint4 vr[2];
  auto vload = [&](int vb) {
    const ushort* Vg = Vb + bh_off + (size_t)(vb * 64) * D_;
    vr[0] = *(const uint4*)&Vg[(size_t)lane * D_ + (size_t)(wave * 2 + 0) * 8];
    vr[1] = *(const uint4*)&Vg[(size_t)lane * D_ + (size_t)(wave * 2 + 1) * 8];
  };
  auto vwrite = [&](int buf) {
#pragma unroll
    for (int it = 0; it < 2; ++it) {
      int seg = wave * 2 + it;
      ushort tmp[8];
      *(uint4*)tmp = vr[it];
#pragma unroll
      for (int e = 0; e < 8; ++e) Vt[buf][(seg * 8 + e) * 64 + (lane ^ (e << 3))] = tmp[e];
    }
  };

  f32x4 zero = {0.f, 0.f, 0.f, 0.f};

  // ================= phase 1: pass1(A) =================
  int cur = 0;
  stage_K(0, 0);
  float pA0 = 0.f, pA1 = 0.f, pA2 = 0.f, pA3 = 0.f;
  for (int vb = 0; vb <= qtA; ++vb) {
    asm volatile("s_waitcnt vmcnt(0)" ::: "memory");
    __builtin_amdgcn_s_barrier();
    if (vb < qtA) stage_K(cur ^ 1, vb + 1);
    const bool diag = (vb == qtA);
#pragma unroll
    for (int jt = 0; jt < 4; ++jt) {
      int krow = jt * 16 + r0;
      bf16x8 kb0 = *(const bf16x8*)&Kt[cur][krow * 64 + ((kq ^ (r0 & 7)) * 8)];
      bf16x8 kb1 = *(const bf16x8*)&Kt[cur][krow * 64 + (((4 + kq) ^ (r0 & 7)) * 8)];
      f32x4 sc = {0.f, 0.f, 0.f, 0.f};
      sc = __builtin_amdgcn_mfma_f32_16x16x32_bf16(kb0, qa0A, sc, 0, 0, 0);
      sc = __builtin_amdgcn_mfma_f32_16x16x32_bf16(kb1, qa1A, sc, 0, 0, 0);
      int k0 = vb * 64 + jt * 16 + kq * 4;
      pA0 += (diag && k0 + 0 > qgA) ? 0.f : exp2f(sc[0] * KSC);
      pA1 += (diag && k0 + 1 > qgA) ? 0.f : exp2f(sc[1] * KSC);
      pA2 += (diag && k0 + 2 > qgA) ? 0.f : exp2f(sc[2] * KSC);
      pA3 += (diag && k0 + 3 > qgA) ? 0.f : exp2f(sc[3] * KSC);
    }
    cur ^= 1;
  }
  float ssumA = (pA0 + pA1) + (pA2 + pA3);
  ssumA += __shfl_xor(ssumA, 16, 64);
  ssumA += __shfl_xor(ssumA, 32, 64);
  const float rsA = 1.f / ssumA;

  // ================= phase 2: pass2(A) fused with pass1(B) =================
  f32x4 caccA[4];
#pragma unroll
  for (int nt = 0; nt < 4; ++nt) caccA[nt] = zero;
  float pB0 = 0.f, pB1 = 0.f, pB2 = 0.f, pB3 = 0.f;

  __syncthreads();
  cur = 0;
  stage_K(0, 0);
  vload(0);
  vwrite(0);
  for (int vb = 0; vb <= qtA; ++vb) {
    if (vb == 0) asm volatile("s_waitcnt vmcnt(0) lgkmcnt(0)" ::: "memory");
    else         asm volatile("s_waitcnt vmcnt(4) lgkmcnt(0)" ::: "memory");
    __builtin_amdgcn_s_barrier();
    if (vb < qtA) { stage_K(cur ^ 1, vb + 1); vload(vb + 1); }
    const bool diagA = (vb == qtA);
    const bool doB = (vb <= qtB);
    const bool diagB = (vb == qtB);
#pragma unroll
    for (int jt = 0; jt < 4; ++jt) {
      int krow = jt * 16 + r0;
      bf16x8 kb0 = *(const bf16x8*)&Kt[cur][krow * 64 + ((kq ^ (r0 & 7)) * 8)];
      bf16x8 kb1 = *(const bf16x8*)&Kt[cur][krow * 64 + (((4 + kq) ^ (r0 & 7)) * 8)];
      int k0 = vb * 64 + jt * 16 + kq * 4;
      f32x4 sc = {0.f, 0.f, 0.f, 0.f};
      sc = __builtin_amdgcn_mfma_f32_16x16x32_bf16(kb0, qa0A, sc, 0, 0, 0);
      sc = __builtin_amdgcn_mfma_f32_16x16x32_bf16(kb1, qa1A, sc, 0, 0, 0);
      float e0 = (diagA && k0 + 0 > qgA) ? 0.f : exp2f(sc[0] * KSC);
      float e1 = (diagA && k0 + 1 > qgA) ? 0.f : exp2f(sc[1] * KSC);
      float e2 = (diagA && k0 + 2 > qgA) ? 0.f : exp2f(sc[2] * KSC);
      float e3 = (diagA && k0 + 3 > qgA) ? 0.f : exp2f(sc[3] * KSC);
      uint2 pk;
      pk.x = cvtpk(e0, e1);
      pk.y = cvtpk(e2, e3);
      int s = (4 * jt + kq) ^ ((r0 & 3) << 2);
      *(uint2*)&Wl[wave][r0 * 64 + s * 4] = pk;
      f32x4 o = {e0 * rsA, e1 * rsA, e2 * rsA, e3 * rsA};
      *(f32x4*)&wbase[(size_t)qgA * S_ + k0] = o;
      if (doB) {
        f32x4 sb = {0.f, 0.f, 0.f, 0.f};
        sb = __builtin_amdgcn_mfma_f32_16x16x32_bf16(kb0, qa0B, sb, 0, 0, 0);
        sb = __builtin_amdgcn_mfma_f32_16x16x32_bf16(kb1, qa1B, sb, 0, 0, 0);
        pB0 += (diagB && k0 + 0 > qgB) ? 0.f : exp2f(sb[0] * KSC);
        pB1 += (diagB && k0 + 1 > qgB) ? 0.f : exp2f(sb[1] * KSC);
        pB2 += (diagB && k0 + 2 > qgB) ? 0.f : exp2f(sb[2] * KSC);
        pB3 += (diagB && k0 + 3 > qgB) ? 0.f : exp2f(sb[3] * KSC);
      }
    }
#pragma unroll
    for (int ks = 0; ks < 2; ++ks) {
      int sB = (8 * ks + 2 * kq) ^ ((r0 & 3) << 2);
      bf16x8 af = *(const bf16x8*)&Wl[wave][r0 * 64 + sB * 4];
#pragma unroll
      for (int nt = 0; nt < 4; ++nt) {
        bf16x8 vf = *(const bf16x8*)&Vt[cur][(nt * 16 + r0) * 64 + (((ks * 4 + kq) ^ (r0 & 7)) * 8)];
        caccA[nt] = __builtin_amdgcn_mfma_f32_16x16x32_bf16(af, vf, caccA[nt], 0, 0, 0);
      }
    }
    if (vb < qtA) vwrite(cur ^ 1);
    cur ^= 1;
  }
  float ssumB = (pB0 + pB1) + (pB2 + pB3);
  ssumB += __shfl_xor(ssumB, 16, 64);
  ssumB += __shfl_xor(ssumB, 32, 64);
  const float rsB = 1.f / ssumB;

  // ---- A epilogue
  {
    int col0 = (qtA + 1) * 64;
    int nf4 = (S_ - col0) >> 2;
    int row = tid >> 2, c = tid & 3;
    f32x4 z4 = {0.f, 0.f, 0.f, 0.f};
    float* rp = &wbase[(size_t)(qtA * 64 + row) * S_];
    for (int i = c; i < nf4; i += 4) *(f32x4*)&rp[col0 + i * 4] = z4;
  }
  {
    float rsj[4];
#pragma unroll
    for (int j = 0; j < 4; ++j) rsj[j] = __shfl(rsA, kq * 4 + j, 64);
    ushort* cg = ctx + ((size_t)(b * S_ + qtA * 64 + wave * 16 + kq * 4)) * D_ + h * 64;
#pragma unroll
    for (int nt = 0; nt < 4; ++nt)
#pragma unroll
      for (int j = 0; j < 4; ++j)
        cg[(size_t)j * D_ + nt * 16 + r0] = f2bf(caccA[nt][j] * rsj[j]);
  }

  // ================= phase 3: pass2(B) =================
  f32x4 caccB[4];
#pragma unroll
  for (int nt = 0; nt < 4; ++nt) caccB[nt] = zero;
  __syncthreads();
  cur = 0;
  stage_K(0, 0);
  vload(0);
  vwrite(0);
  for (int vb = 0; vb <= qtB; ++vb) {
    if (vb == 0) asm volatile("s_waitcnt vmcnt(0) lgkmcnt(0)" ::: "memory");
    else         asm volatile("s_waitcnt vmcnt(4) lgkmcnt(0)" ::: "memory");
    __builtin_amdgcn_s_barrier();
    if (vb < qtB) { stage_K(cur ^ 1, vb + 1); vload(vb + 1); }
    const bool diag = (vb == qtB);
#pragma unroll
    for (int jt = 0; jt < 4; ++jt) {
      int krow = jt * 16 + r0;
      bf16x8 kb0 = *(const bf16x8*)&Kt[cur][krow * 64 + ((kq ^ (r0 & 7)) * 8)];
      bf16x8 kb1 = *(const bf16x8*)&Kt[cur][krow * 64 + (((4 + kq) ^ (r0 & 7)) * 8)];
      f32x4 sc = {0.f, 0.f, 0.f, 0.f};
      sc = __builtin_amdgcn_mfma_f32_16x16x32_bf16(kb0, qa0B, sc, 0, 0, 0);
      sc = __builtin_amdgcn_mfma_f32_16x16x32_bf16(kb1, qa1B, sc, 0, 0, 0);
      int k0 = vb * 64 + jt * 16 + kq * 4;
      float e0 = (diag && k0 + 0 > qgB) ? 0.f : exp2f(sc[0] * KSC);
      float e1 = (diag && k0 + 1 > qgB) ? 0.f : exp2f(sc[1] * KSC);
      float e2 = (diag && k0 + 2 > qgB) ? 0.f : exp2f(sc[2] * KSC);
      float e3 = (diag && k0 + 3 > qgB) ? 0.f : exp2f(sc[3] * KSC);
      uint2 pk;
      pk.x = cvtpk(e0, e1);
      pk.y = cvtpk(e2, e3);
      int s = (4 * jt + kq) ^ ((r0 & 3) << 2);
      *(uint2*)&Wl[wave][r0 * 64 + s * 4] = pk;
      f32x4 o = {e0 * rsB, e1 * rsB, e2 * rsB, e3 * rsB};
      *(f32x4*)&wbase[(size_t)qgB * S_ + k0] = o;
    }
#pragma unroll
    for (int ks = 0; ks < 2; ++ks) {
      int sB = (8 * ks + 2 * kq) ^ ((r0 & 3) << 2);
      bf16x8 af = *(const bf16x8*)&Wl[wave][r0 * 64 + sB * 4];
#pragma unroll
      for (int nt = 0; nt < 4; ++nt) {
        bf16x8 vf = *(const bf16x8*)&Vt[cur][(nt * 16 + r0) * 64 + (((ks * 4 + kq) ^ (r0 & 7)) * 8)];
        caccB[nt] = __builtin_amdgcn_mfma_f32_16x16x32_bf16(af, vf, caccB[nt], 0, 0, 0);
      }
    }
    if (vb < qtB) vwrite(cur ^ 1);
    cur ^= 1;
  }

  // ---- B epilogue
  {
    int col0 = (qtB + 1) * 64;
    int nf4 = (S_ - col0) >> 2;
    int row = tid >> 2, c = tid & 3;
    f32x4 z4 = {0.f, 0.f, 0.f, 0.f};
    float* rp = &wbase[(size_t)(qtB * 64 + row) * S_];
    for (int i = c; i < nf4; i += 4) *(f32x4*)&rp[col0 + i * 4] = z4;
  }
  {
    float rsj[4];
#pragma unroll
    for (int j = 0; j < 4; ++j) rsj[j] = __shfl(rsB, kq * 4 + j, 64);
    ushort* cg = ctx + ((size_t)(b * S_ + qtB * 64 + wave * 16 + kq * 4)) * D_ + h * 64;
#pragma unroll
    for (int nt = 0; nt < 4; ++nt)
#pragma unroll
      for (int j = 0; j < 4; ++j)
        cg[(size_t)j * D_ + nt * 16 + r0] = f2bf(caccB[nt][j] * rsj[j]);
  }
}

extern "C" void kernel_launch(void* const* d_in, const int* in_sizes, int n_in,
                              void* d_out, int out_size, void* d_ws, size_t ws_size,
                              hipStream_t stream) {
  const float* q    = (const float*)d_in[0];
  const float* k    = (const float*)d_in[1];
  const float* v    = (const float*)d_in[2];
  const float* Wq   = (const float*)d_in[4];
  const float* bq   = (const float*)d_in[5];
  const float* Wk   = (const float*)d_in[6];
  const float* bk   = (const float*)d_in[7];
  const float* Wv   = (const float*)d_in[8];
  const float* bv   = (const float*)d_in[9];
  const float* Wo   = (const float*)d_in[10];
  const float* bo   = (const float*)d_in[11];

  char* ws = (char*)d_ws;
  const size_t MB = 1024 * 1024;
  ushort* WqT    = (ushort*)(ws + 24 * MB);
  ushort* WkT    = (ushort*)(ws + 26 * MB);
  ushort* WvT    = (ushort*)(ws + 28 * MB);
  ushort* WoT    = (ushort*)(ws + 30 * MB);
  ushort* Q_bf   = (ushort*)(ws + 32 * MB);
  ushort* K_bf   = (ushort*)(ws + 40 * MB);
  ushort* V_bf   = (ushort*)(ws + 48 * MB);
  ushort* ctx_bf = (ushort*)(ws + 56 * MB);

  float* out  = (float*)d_out;
  float* wout = out + (size_t)M_ * D_;

  trW<<<dim3(32, 32, 4), 256, 0, stream>>>(Wq, Wk, Wv, Wo, WqT, WkT, WvT, WoT);
  gemm_qkv<<<dim3(M_ / 64, D_ / 128, 3), 256, 0, stream>>>(
      q, k, v, WqT, WkT, WvT, bq, bk, bv, Q_bf, K_bf, V_bf);
  // DIAGNOSTIC this round: attn launched twice (idempotent) to measure T_attn
  // from the total-time delta. Will be removed next round.
  attn_fused<<<dim3(512), 256, 0, stream>>>(Q_bf, K_bf, V_bf, wout, ctx_bf);
  attn_fused<<<dim3(512), 256, 0, stream>>>(Q_bf, K_bf, V_bf, wout, ctx_bf);
  gemm_out<<<dim3(M_ / 64, D_ / 64), 256, 0, stream>>>(ctx_bf, WoT, bo, out);
}

// Round 15
// 192.305 us; speedup vs baseline: 1.2495x; 1.2495x over previous
//
#include <hip/hip_runtime.h>
#include <hip/hip_bf16.h>

#define B_ 4
#define S_ 1024
#define D_ 1024
#define H_ 16
#define HD_ 64
#define M_ (B_*S_)
#define NT_ (S_/64)   // 16 k/v tiles

typedef __attribute__((ext_vector_type(8))) short bf16x8;
typedef __attribute__((ext_vector_type(8))) unsigned short u16x8;
typedef __attribute__((ext_vector_type(4))) float f32x4;

typedef __attribute__((address_space(1))) const unsigned int g_uint;
typedef __attribute__((address_space(3))) unsigned int l_uint;

__device__ __forceinline__ unsigned short f2bf(float f) {
  unsigned int x = __builtin_bit_cast(unsigned int, f);
  unsigned int r = (x + 0x7fffu + ((x >> 16) & 1u)) >> 16;
  return (unsigned short)r;
}
__device__ __forceinline__ float bf2f(unsigned short u) {
  unsigned int x = ((unsigned int)u) << 16;
  return __builtin_bit_cast(float, x);
}
__device__ __forceinline__ unsigned int cvtpk(float lo, float hi) {
  unsigned int r;
  asm("v_cvt_pk_bf16_f32 %0, %1, %2" : "=v"(r) : "v"(lo), "v"(hi));
  return r;
}
__device__ __forceinline__ void load_lds16(const ushort* g, ushort* l) {
  __builtin_amdgcn_global_load_lds((g_uint*)g, (l_uint*)l, 16, 0, 0);
}
// non-temporal 16B store: no L2 allocation -> keeps K/V panels L2-resident
__device__ __forceinline__ void store_nt(float* p, f32x4 v) {
  __builtin_nontemporal_store(v, (f32x4*)p);
}

// ---------------- W -> W^T bf16 (weights only; q/k/v cvt fused into gemm_qkv) ----
__global__ void trW(const float* __restrict__ Wq, const float* __restrict__ Wk,
                    const float* __restrict__ Wv, const float* __restrict__ Wo,
                    ushort* __restrict__ q, ushort* __restrict__ k,
                    ushort* __restrict__ v, ushort* __restrict__ o) {
  const float* W; ushort* WT;
  switch (blockIdx.z) {
    case 0: W = Wq; WT = q; break;
    case 1: W = Wk; WT = k; break;
    case 2: W = Wv; WT = v; break;
    default: W = Wo; WT = o; break;
  }
  __shared__ float tile[32][33];
  int tx = threadIdx.x & 31, ty = threadIdx.x >> 5;
  int bx = blockIdx.x * 32, by = blockIdx.y * 32;
  for (int r = 0; r < 32; r += 8)
    tile[ty + r][tx] = W[(size_t)(by + ty + r) * D_ + bx + tx];
  __syncthreads();
  for (int r = 0; r < 32; r += 8)
    WT[(size_t)(bx + ty + r) * D_ + by + tx] = f2bf(tile[tx][ty + r]);
}

// ---------------- bf16 MFMA GEMM: C[BM,BN] = A[M,K]*Bt[N,K]^T + bias ----------------
// AFP32: A is fp32 in global; staged via reg (float4 x2 -> cvt_pk -> ds_write_b128)
// into the SAME linear LDS layout global_load_lds produces (source swizzle sc8).
template <int BF16OUT, int BM, int BN, int AFP32>
__device__ __forceinline__ void gemm_body(const void* __restrict__ Ap,
                                          const ushort* __restrict__ Bt,
                                          const float* __restrict__ bias,
                                          void* __restrict__ Cp,
                                          int bm, int bn, int N, int K) {
  __shared__ ushort Al[BM * 64];
  __shared__ ushort Bl[BN * 64];
  constexpr int MF = BM / 32;   // a-frags / acc rows per wave
  constexpr int NF = BN / 32;   // b-frags / acc cols per wave
  const int tid = threadIdx.x;
  const int wave = tid >> 6, lane = tid & 63;
  const int r0 = lane & 15, kq = lane >> 4;
  const int wr = wave >> 1, wc = wave & 1;
  const int sl = lane >> 3;
  const int sc8 = ((lane & 7) ^ sl) * 8;   // swizzled source col (elements)
  f32x4 zero = {0.f, 0.f, 0.f, 0.f};
  f32x4 acc[MF][NF];
#pragma unroll
  for (int m = 0; m < MF; ++m)
#pragma unroll
    for (int n = 0; n < NF; ++n) acc[m][n] = zero;

  for (int kt = 0; kt < K; kt += 64) {
    __syncthreads();
    if (AFP32) {
      const float* A = (const float*)Ap;
#pragma unroll
      for (int i = 0; i < MF; ++i) {
        int c = wave * MF + i;
        const float* src = &A[(size_t)(bm + c * 8 + sl) * K + kt + sc8];
        float4 f0 = *(const float4*)src;
        float4 f1 = *(const float4*)(src + 4);
        uint4 pk;
        pk.x = cvtpk(f0.x, f0.y);
        pk.y = cvtpk(f0.z, f0.w);
        pk.z = cvtpk(f1.x, f1.y);
        pk.w = cvtpk(f1.z, f1.w);
        *(uint4*)&Al[c * 512 + lane * 8] = pk;   // linear dest = gload_lds layout
      }
    } else {
      const ushort* A = (const ushort*)Ap;
#pragma unroll
      for (int i = 0; i < MF; ++i) {
        int c = wave * MF + i;
        load_lds16(A + (size_t)(bm + c * 8 + sl) * K + kt + sc8, &Al[c * 512]);
      }
    }
#pragma unroll
    for (int i = 0; i < NF; ++i) {
      int c = wave * NF + i;
      load_lds16(Bt + (size_t)(bn + c * 8 + sl) * K + kt + sc8, &Bl[c * 512]);
    }
    __syncthreads();
#pragma unroll
    for (int kk = 0; kk < 2; ++kk) {
      bf16x8 a[MF], b[NF];
#pragma unroll
      for (int m = 0; m < MF; ++m)
        a[m] = *(const bf16x8*)&Al[(wr * (BM / 2) + m * 16 + r0) * 64 + (((kk * 4 + kq) ^ (r0 & 7)) * 8)];
#pragma unroll
      for (int n = 0; n < NF; ++n)
        b[n] = *(const bf16x8*)&Bl[(wc * (BN / 2) + n * 16 + r0) * 64 + (((kk * 4 + kq) ^ (r0 & 7)) * 8)];
#pragma unroll
      for (int m = 0; m < MF; ++m)
#pragma unroll
        for (int n = 0; n < NF; ++n)
          acc[m][n] = __builtin_amdgcn_mfma_f32_16x16x32_bf16(a[m], b[n], acc[m][n], 0, 0, 0);
    }
  }

#pragma unroll
  for (int m = 0; m < MF; ++m) {
#pragma unroll
    for (int n = 0; n < NF; ++n) {
      int col = bn + wc * (BN / 2) + n * 16 + r0;
      float bv = bias[col];
#pragma unroll
      for (int j = 0; j < 4; ++j) {
        int row = bm + wr * (BM / 2) + m * 16 + kq * 4 + j;
        float v = acc[m][n][j] + bv;
        if (BF16OUT) ((ushort*)Cp)[(size_t)row * N + col] = f2bf(v);
        else         ((float*)Cp)[(size_t)row * N + col] = v;
      }
    }
  }
}

__global__ __launch_bounds__(256) void gemm_qkv(const float* __restrict__ qa,
                                                const float* __restrict__ ka,
                                                const float* __restrict__ va,
                                                const ushort* __restrict__ WqT,
                                                const ushort* __restrict__ WkT,
                                                const ushort* __restrict__ WvT,
                                                const float* __restrict__ bq,
                                                const float* __restrict__ bk,
                                                const float* __restrict__ bv,
                                                ushort* __restrict__ Qo,
                                                ushort* __restrict__ Ko,
                                                ushort* __restrict__ Vo) {
  const float* A; const ushort* Bt; const float* bias; ushort* C;
  switch (blockIdx.z) {
    case 0: A = qa; Bt = WqT; bias = bq; C = Qo; break;
    case 1: A = ka; Bt = WkT; bias = bk; C = Ko; break;
    default: A = va; Bt = WvT; bias = bv; C = Vo; break;
  }
  gemm_body<1, 64, 128, 1>(A, Bt, bias, C, blockIdx.x * 64, blockIdx.y * 128, D_, D_);
}

__global__ __launch_bounds__(256) void gemm_out(const ushort* __restrict__ A,
                                                const ushort* __restrict__ Bt,
                                                const float* __restrict__ bias,
                                                float* __restrict__ C) {
  gemm_body<0, 64, 64, 0>(A, Bt, bias, C, blockIdx.x * 64, blockIdx.y * 64, D_, D_);
}

// ---------------- fused attention, PAIRED q-tiles (qtA=15-p heavy, qtB=p light) ----
// grid 512: id&63 = (b,h) -> XCD-local K/V panel; p = id>>6 (heavy pairs first).
// ALL d_out weight stores are NON-TEMPORAL: the 268MB write stream must not
// evict the 2MB/XCD K/V panels from L2 (r14 diagnostic: attn is HBM-read-bound
// because pass-2 K/V re-reads miss L2).
__global__ __launch_bounds__(256) void attn_fused(const ushort* __restrict__ Qb,
                                                  const ushort* __restrict__ Kb,
                                                  const ushort* __restrict__ Vb,
                                                  float* __restrict__ wout,
                                                  ushort* __restrict__ ctx) {
  const int id = blockIdx.x;
  const int bh = id & 63;
  const int b = bh >> 4, h = bh & 15;
  const int p = id >> 6;
  const int qtA = NT_ - 1 - p;   // 8..15
  const int qtB = p;             // 0..7  (qtB < qtA always)
  const int tid = threadIdx.x, wave = tid >> 6, lane = tid & 63;
  const int r0 = lane & 15, kq = lane >> 4;
  const int sl = lane >> 3;
  const int sc8 = ((lane & 7) ^ sl) * 8;
  __shared__ ushort Kt[2][64 * 64];   // dbuf, both-sides swizzle slot^=(row&7)
  __shared__ ushort Vt[2][64 * 64];   // dbuf, V^T [d][k], col^=(d&7)<<3
  __shared__ ushort Wl[4][16 * 64];   // per-wave P tile, 8B-slot swizzle
  const size_t bh_off = ((size_t)(b * S_)) * D_ + (size_t)h * 64;
  float* wbase = wout + (size_t)bh * S_ * S_;
  const float KSC = 0.18033688011f;   // 0.125 * log2(e)

  const ushort* QgA = Qb + bh_off + (size_t)(qtA * 64 + wave * 16 + r0) * D_ + kq * 8;
  bf16x8 qa0A = *(const bf16x8*)QgA;
  bf16x8 qa1A = *(const bf16x8*)(QgA + 32);
  const ushort* QgB = Qb + bh_off + (size_t)(qtB * 64 + wave * 16 + r0) * D_ + kq * 8;
  bf16x8 qa0B = *(const bf16x8*)QgB;
  bf16x8 qa1B = *(const bf16x8*)(QgB + 32);
  const int qgA = qtA * 64 + wave * 16 + r0;
  const int qgB = qtB * 64 + wave * 16 + r0;

  auto stage_K = [&](int buf, int vb) {
    const ushort* Kg = Kb + bh_off + (size_t)(vb * 64) * D_;
#pragma unroll
    for (int i = 0; i < 2; ++i) {
      int c = wave * 2 + i;
      load_lds16(Kg + (size_t)(c * 8 + sl) * D_ + sc8, &Kt[buf][c * 512]);
    }
  };
  uint4 vr[2];
  auto vload = [&](int vb) {
    const ushort* Vg = Vb + bh_off + (size_t)(vb * 64) * D_;
    vr[0] = *(const uint4*)&Vg[(size_t)lane * D_ + (size_t)(wave * 2 + 0) * 8];
    vr[1] = *(const uint4*)&Vg[(size_t)lane * D_ + (size_t)(wave * 2 + 1) * 8];
  };
  auto vwrite = [&](int buf) {
#pragma unroll
    for (int it = 0; it < 2; ++it) {
      int seg = wave * 2 + it;
      ushort tmp[8];
      *(uint4*)tmp = vr[it];
#pragma unroll
      for (int e = 0; e < 8; ++e) Vt[buf][(seg * 8 + e) * 64 + (lane ^ (e << 3))] = tmp[e];
    }
  };

  f32x4 zero = {0.f, 0.f, 0.f, 0.f};

  // ================= phase 1: pass1(A) =================
  int cur = 0;
  stage_K(0, 0);
  float pA0 = 0.f, pA1 = 0.f, pA2 = 0.f, pA3 = 0.f;
  for (int vb = 0; vb <= qtA; ++vb) {
    asm volatile("s_waitcnt vmcnt(0)" ::: "memory");
    __builtin_amdgcn_s_barrier();
    if (vb < qtA) stage_K(cur ^ 1, vb + 1);
    const bool diag = (vb == qtA);
#pragma unroll
    for (int jt = 0; jt < 4; ++jt) {
      int krow = jt * 16 + r0;
      bf16x8 kb0 = *(const bf16x8*)&Kt[cur][krow * 64 + ((kq ^ (r0 & 7)) * 8)];
      bf16x8 kb1 = *(const bf16x8*)&Kt[cur][krow * 64 + (((4 + kq) ^ (r0 & 7)) * 8)];
      f32x4 sc = {0.f, 0.f, 0.f, 0.f};
      sc = __builtin_amdgcn_mfma_f32_16x16x32_bf16(kb0, qa0A, sc, 0, 0, 0);
      sc = __builtin_amdgcn_mfma_f32_16x16x32_bf16(kb1, qa1A, sc, 0, 0, 0);
      int k0 = vb * 64 + jt * 16 + kq * 4;
      pA0 += (diag && k0 + 0 > qgA) ? 0.f : exp2f(sc[0] * KSC);
      pA1 += (diag && k0 + 1 > qgA) ? 0.f : exp2f(sc[1] * KSC);
      pA2 += (diag && k0 + 2 > qgA) ? 0.f : exp2f(sc[2] * KSC);
      pA3 += (diag && k0 + 3 > qgA) ? 0.f : exp2f(sc[3] * KSC);
    }
    cur ^= 1;
  }
  float ssumA = (pA0 + pA1) + (pA2 + pA3);
  ssumA += __shfl_xor(ssumA, 16, 64);
  ssumA += __shfl_xor(ssumA, 32, 64);
  const float rsA = 1.f / ssumA;

  // ================= phase 2: pass2(A) fused with pass1(B) =================
  f32x4 caccA[4];
#pragma unroll
  for (int nt = 0; nt < 4; ++nt) caccA[nt] = zero;
  float pB0 = 0.f, pB1 = 0.f, pB2 = 0.f, pB3 = 0.f;

  __syncthreads();
  cur = 0;
  stage_K(0, 0);
  vload(0);
  vwrite(0);
  for (int vb = 0; vb <= qtA; ++vb) {
    if (vb == 0) asm volatile("s_waitcnt vmcnt(0) lgkmcnt(0)" ::: "memory");
    else         asm volatile("s_waitcnt vmcnt(4) lgkmcnt(0)" ::: "memory");
    __builtin_amdgcn_s_barrier();
    if (vb < qtA) { stage_K(cur ^ 1, vb + 1); vload(vb + 1); }
    const bool diagA = (vb == qtA);
    const bool doB = (vb <= qtB);
    const bool diagB = (vb == qtB);
#pragma unroll
    for (int jt = 0; jt < 4; ++jt) {
      int krow = jt * 16 + r0;
      bf16x8 kb0 = *(const bf16x8*)&Kt[cur][krow * 64 + ((kq ^ (r0 & 7)) * 8)];
      bf16x8 kb1 = *(const bf16x8*)&Kt[cur][krow * 64 + (((4 + kq) ^ (r0 & 7)) * 8)];
      int k0 = vb * 64 + jt * 16 + kq * 4;
      f32x4 sc = {0.f, 0.f, 0.f, 0.f};
      sc = __builtin_amdgcn_mfma_f32_16x16x32_bf16(kb0, qa0A, sc, 0, 0, 0);
      sc = __builtin_amdgcn_mfma_f32_16x16x32_bf16(kb1, qa1A, sc, 0, 0, 0);
      float e0 = (diagA && k0 + 0 > qgA) ? 0.f : exp2f(sc[0] * KSC);
      float e1 = (diagA && k0 + 1 > qgA) ? 0.f : exp2f(sc[1] * KSC);
      float e2 = (diagA && k0 + 2 > qgA) ? 0.f : exp2f(sc[2] * KSC);
      float e3 = (diagA && k0 + 3 > qgA) ? 0.f : exp2f(sc[3] * KSC);
      uint2 pk;
      pk.x = cvtpk(e0, e1);
      pk.y = cvtpk(e2, e3);
      int s = (4 * jt + kq) ^ ((r0 & 3) << 2);
      *(uint2*)&Wl[wave][r0 * 64 + s * 4] = pk;
      f32x4 o = {e0 * rsA, e1 * rsA, e2 * rsA, e3 * rsA};
      store_nt(&wbase[(size_t)qgA * S_ + k0], o);
      if (doB) {
        f32x4 sb = {0.f, 0.f, 0.f, 0.f};
        sb = __builtin_amdgcn_mfma_f32_16x16x32_bf16(kb0, qa0B, sb, 0, 0, 0);
        sb = __builtin_amdgcn_mfma_f32_16x16x32_bf16(kb1, qa1B, sb, 0, 0, 0);
        pB0 += (diagB && k0 + 0 > qgB) ? 0.f : exp2f(sb[0] * KSC);
        pB1 += (diagB && k0 + 1 > qgB) ? 0.f : exp2f(sb[1] * KSC);
        pB2 += (diagB && k0 + 2 > qgB) ? 0.f : exp2f(sb[2] * KSC);
        pB3 += (diagB && k0 + 3 > qgB) ? 0.f : exp2f(sb[3] * KSC);
      }
    }
#pragma unroll
    for (int ks = 0; ks < 2; ++ks) {
      int sB = (8 * ks + 2 * kq) ^ ((r0 & 3) << 2);
      bf16x8 af = *(const bf16x8*)&Wl[wave][r0 * 64 + sB * 4];
#pragma unroll
      for (int nt = 0; nt < 4; ++nt) {
        bf16x8 vf = *(const bf16x8*)&Vt[cur][(nt * 16 + r0) * 64 + (((ks * 4 + kq) ^ (r0 & 7)) * 8)];
        caccA[nt] = __builtin_amdgcn_mfma_f32_16x16x32_bf16(af, vf, caccA[nt], 0, 0, 0);
      }
    }
    if (vb < qtA) vwrite(cur ^ 1);
    cur ^= 1;
  }
  float ssumB = (pB0 + pB1) + (pB2 + pB3);
  ssumB += __shfl_xor(ssumB, 16, 64);
  ssumB += __shfl_xor(ssumB, 32, 64);
  const float rsB = 1.f / ssumB;

  // ---- A epilogue (zero region empty for qtA=15; nt stores)
  {
    int col0 = (qtA + 1) * 64;
    int nf4 = (S_ - col0) >> 2;
    int row = tid >> 2, c = tid & 3;
    f32x4 z4 = {0.f, 0.f, 0.f, 0.f};
    float* rp = &wbase[(size_t)(qtA * 64 + row) * S_];
    for (int i = c; i < nf4; i += 4) store_nt(&rp[col0 + i * 4], z4);
  }
  {
    float rsj[4];
#pragma unroll
    for (int j = 0; j < 4; ++j) rsj[j] = __shfl(rsA, kq * 4 + j, 64);
    ushort* cg = ctx + ((size_t)(b * S_ + qtA * 64 + wave * 16 + kq * 4)) * D_ + h * 64;
#pragma unroll
    for (int nt = 0; nt < 4; ++nt)
#pragma unroll
      for (int j = 0; j < 4; ++j)
        cg[(size_t)j * D_ + nt * 16 + r0] = f2bf(caccA[nt][j] * rsj[j]);
  }

  // ================= phase 3: pass2(B) =================
  f32x4 caccB[4];
#pragma unroll
  for (int nt = 0; nt < 4; ++nt) caccB[nt] = zero;
  __syncthreads();
  cur = 0;
  stage_K(0, 0);
  vload(0);
  vwrite(0);
  for (int vb = 0; vb <= qtB; ++vb) {
    if (vb == 0) asm volatile("s_waitcnt vmcnt(0) lgkmcnt(0)" ::: "memory");
    else         asm volatile("s_waitcnt vmcnt(4) lgkmcnt(0)" ::: "memory");
    __builtin_amdgcn_s_barrier();
    if (vb < qtB) { stage_K(cur ^ 1, vb + 1); vload(vb + 1); }
    const bool diag = (vb == qtB);
#pragma unroll
    for (int jt = 0; jt < 4; ++jt) {
      int krow = jt * 16 + r0;
      bf16x8 kb0 = *(const bf16x8*)&Kt[cur][krow * 64 + ((kq ^ (r0 & 7)) * 8)];
      bf16x8 kb1 = *(const bf16x8*)&Kt[cur][krow * 64 + (((4 + kq) ^ (r0 & 7)) * 8)];
      f32x4 sc = {0.f, 0.f, 0.f, 0.f};
      sc = __builtin_amdgcn_mfma_f32_16x16x32_bf16(kb0, qa0B, sc, 0, 0, 0);
      sc = __builtin_amdgcn_mfma_f32_16x16x32_bf16(kb1, qa1B, sc, 0, 0, 0);
      int k0 = vb * 64 + jt * 16 + kq * 4;
      float e0 = (diag && k0 + 0 > qgB) ? 0.f : exp2f(sc[0] * KSC);
      float e1 = (diag && k0 + 1 > qgB) ? 0.f : exp2f(sc[1] * KSC);
      float e2 = (diag && k0 + 2 > qgB) ? 0.f : exp2f(sc[2] * KSC);
      float e3 = (diag && k0 + 3 > qgB) ? 0.f : exp2f(sc[3] * KSC);
      uint2 pk;
      pk.x = cvtpk(e0, e1);
      pk.y = cvtpk(e2, e3);
      int s = (4 * jt + kq) ^ ((r0 & 3) << 2);
      *(uint2*)&Wl[wave][r0 * 64 + s * 4] = pk;
      f32x4 o = {e0 * rsB, e1 * rsB, e2 * rsB, e3 * rsB};
      store_nt(&wbase[(size_t)qgB * S_ + k0], o);
    }
#pragma unroll
    for (int ks = 0; ks < 2; ++ks) {
      int sB = (8 * ks + 2 * kq) ^ ((r0 & 3) << 2);
      bf16x8 af = *(const bf16x8*)&Wl[wave][r0 * 64 + sB * 4];
#pragma unroll
      for (int nt = 0; nt < 4; ++nt) {
        bf16x8 vf = *(const bf16x8*)&Vt[cur][(nt * 16 + r0) * 64 + (((ks * 4 + kq) ^ (r0 & 7)) * 8)];
        caccB[nt] = __builtin_amdgcn_mfma_f32_16x16x32_bf16(af, vf, caccB[nt], 0, 0, 0);
      }
    }
    if (vb < qtB) vwrite(cur ^ 1);
    cur ^= 1;
  }

  // ---- B epilogue (large zero region; nt stores)
  {
    int col0 = (qtB + 1) * 64;
    int nf4 = (S_ - col0) >> 2;
    int row = tid >> 2, c = tid & 3;
    f32x4 z4 = {0.f, 0.f, 0.f, 0.f};
    float* rp = &wbase[(size_t)(qtB * 64 + row) * S_];
    for (int i = c; i < nf4; i += 4) store_nt(&rp[col0 + i * 4], z4);
  }
  {
    float rsj[4];
#pragma unroll
    for (int j = 0; j < 4; ++j) rsj[j] = __shfl(rsB, kq * 4 + j, 64);
    ushort* cg = ctx + ((size_t)(b * S_ + qtB * 64 + wave * 16 + kq * 4)) * D_ + h * 64;
#pragma unroll
    for (int nt = 0; nt < 4; ++nt)
#pragma unroll
      for (int j = 0; j < 4; ++j)
        cg[(size_t)j * D_ + nt * 16 + r0] = f2bf(caccB[nt][j] * rsj[j]);
  }
}

extern "C" void kernel_launch(void* const* d_in, const int* in_sizes, int n_in,
                              void* d_out, int out_size, void* d_ws, size_t ws_size,
                              hipStream_t stream) {
  const float* q    = (const float*)d_in[0];
  const float* k    = (const float*)d_in[1];
  const float* v    = (const float*)d_in[2];
  const float* Wq   = (const float*)d_in[4];
  const float* bq   = (const float*)d_in[5];
  const float* Wk   = (const float*)d_in[6];
  const float* bk   = (const float*)d_in[7];
  const float* Wv   = (const float*)d_in[8];
  const float* bv   = (const float*)d_in[9];
  const float* Wo   = (const float*)d_in[10];
  const float* bo   = (const float*)d_in[11];

  char* ws = (char*)d_ws;
  const size_t MB = 1024 * 1024;
  ushort* WqT    = (ushort*)(ws + 24 * MB);
  ushort* WkT    = (ushort*)(ws + 26 * MB);
  ushort* WvT    = (ushort*)(ws + 28 * MB);
  ushort* WoT    = (ushort*)(ws + 30 * MB);
  ushort* Q_bf   = (ushort*)(ws + 32 * MB);
  ushort* K_bf   = (ushort*)(ws + 40 * MB);
  ushort* V_bf   = (ushort*)(ws + 48 * MB);
  ushort* ctx_bf = (ushort*)(ws + 56 * MB);

  float* out  = (float*)d_out;
  float* wout = out + (size_t)M_ * D_;

  trW<<<dim3(32, 32, 4), 256, 0, stream>>>(Wq, Wk, Wv, Wo, WqT, WkT, WvT, WoT);
  gemm_qkv<<<dim3(M_ / 64, D_ / 128, 3), 256, 0, stream>>>(
      q, k, v, WqT, WkT, WvT, bq, bk, bv, Q_bf, K_bf, V_bf);
  attn_fused<<<dim3(512), 256, 0, stream>>>(Q_bf, K_bf, V_bf, wout, ctx_bf);
  gemm_out<<<dim3(M_ / 64, D_ / 64), 256, 0, stream>>>(ctx_bf, WoT, bo, out);
}

// Round 16
// 178.088 us; speedup vs baseline: 1.3492x; 1.0798x over previous
//
#include <hip/hip_runtime.h>
#include <hip/hip_bf16.h>

#define B_ 4
#define S_ 1024
#define D_ 1024
#define H_ 16
#define HD_ 64
#define M_ (B_*S_)
#define NT_ (S_/64)   // 16 k/v tiles

typedef __attribute__((ext_vector_type(8))) short bf16x8;
typedef __attribute__((ext_vector_type(8))) unsigned short u16x8;
typedef __attribute__((ext_vector_type(4))) float f32x4;

typedef __attribute__((address_space(1))) const unsigned int g_uint;
typedef __attribute__((address_space(3))) unsigned int l_uint;

__device__ __forceinline__ unsigned short f2bf(float f) {
  unsigned int x = __builtin_bit_cast(unsigned int, f);
  unsigned int r = (x + 0x7fffu + ((x >> 16) & 1u)) >> 16;
  return (unsigned short)r;
}
__device__ __forceinline__ float bf2f(unsigned short u) {
  unsigned int x = ((unsigned int)u) << 16;
  return __builtin_bit_cast(float, x);
}
__device__ __forceinline__ unsigned int cvtpk(float lo, float hi) {
  unsigned int r;
  asm("v_cvt_pk_bf16_f32 %0, %1, %2" : "=v"(r) : "v"(lo), "v"(hi));
  return r;
}
__device__ __forceinline__ void load_lds16(const ushort* g, ushort* l) {
  __builtin_amdgcn_global_load_lds((g_uint*)g, (l_uint*)l, 16, 0, 0);
}

// ---------------- W -> W^T bf16 (weights only; q/k/v cvt fused into gemm_qkv) ----
__global__ void trW(const float* __restrict__ Wq, const float* __restrict__ Wk,
                    const float* __restrict__ Wv, const float* __restrict__ Wo,
                    ushort* __restrict__ q, ushort* __restrict__ k,
                    ushort* __restrict__ v, ushort* __restrict__ o) {
  const float* W; ushort* WT;
  switch (blockIdx.z) {
    case 0: W = Wq; WT = q; break;
    case 1: W = Wk; WT = k; break;
    case 2: W = Wv; WT = v; break;
    default: W = Wo; WT = o; break;
  }
  __shared__ float tile[32][33];
  int tx = threadIdx.x & 31, ty = threadIdx.x >> 5;
  int bx = blockIdx.x * 32, by = blockIdx.y * 32;
  for (int r = 0; r < 32; r += 8)
    tile[ty + r][tx] = W[(size_t)(by + ty + r) * D_ + bx + tx];
  __syncthreads();
  for (int r = 0; r < 32; r += 8)
    WT[(size_t)(bx + ty + r) * D_ + by + tx] = f2bf(tile[tx][ty + r]);
}

// ---- zero one 64x64 fp32 tile of the masked weights region.
// zid in [0, 7680): bh = zid/120, triangle index w = zid%120 -> (qt, colt).
__device__ __forceinline__ void zero_tile(float* __restrict__ wout, int zid, int tid) {
  int bh = zid / 120;
  int w = zid - bh * 120;
  int qt = 0;
  while (w >= 15 - qt) { w -= 15 - qt; ++qt; }   // <=15 iterations
  int colt = qt + 1 + w;
  float* base = wout + (size_t)bh * S_ * S_ +
                (size_t)(qt * 64 + (tid >> 2)) * S_ + colt * 64 + (tid & 3) * 16;
  f32x4 z = {0.f, 0.f, 0.f, 0.f};
  *(f32x4*)&base[0]  = z;
  *(f32x4*)&base[4]  = z;
  *(f32x4*)&base[8]  = z;
  *(f32x4*)&base[12] = z;
}

// ---------------- bf16 MFMA GEMM: C[BM,BN] = A[M,K]*Bt[N,K]^T + bias ----------------
// AFP32: A fp32 in global, reg-staged (float4 x2 -> cvt_pk -> ds_write_b128) into
// the same linear LDS layout global_load_lds produces (source swizzle sc8).
// DOZERO: interleave masked-region zero-fill tiles into the K-loop (write pipe
// is idle in this compute-bound kernel; moves 134MB off the BW-bound attn).
template <int BF16OUT, int BM, int BN, int AFP32, int DOZERO>
__device__ __forceinline__ void gemm_body(const void* __restrict__ Ap,
                                          const ushort* __restrict__ Bt,
                                          const float* __restrict__ bias,
                                          void* __restrict__ Cp,
                                          int bm, int bn, int N, int K,
                                          float* __restrict__ zwout, int zid0) {
  __shared__ ushort Al[BM * 64];
  __shared__ ushort Bl[BN * 64];
  constexpr int MF = BM / 32;
  constexpr int NF = BN / 32;
  const int tid = threadIdx.x;
  const int wave = tid >> 6, lane = tid & 63;
  const int r0 = lane & 15, kq = lane >> 4;
  const int wr = wave >> 1, wc = wave & 1;
  const int sl = lane >> 3;
  const int sc8 = ((lane & 7) ^ sl) * 8;
  f32x4 zero = {0.f, 0.f, 0.f, 0.f};
  f32x4 acc[MF][NF];
#pragma unroll
  for (int m = 0; m < MF; ++m)
#pragma unroll
    for (int n = 0; n < NF; ++n) acc[m][n] = zero;

  for (int kt = 0; kt < K; kt += 64) {
    __syncthreads();
    if (AFP32) {
      const float* A = (const float*)Ap;
#pragma unroll
      for (int i = 0; i < MF; ++i) {
        int c = wave * MF + i;
        const float* src = &A[(size_t)(bm + c * 8 + sl) * K + kt + sc8];
        float4 f0 = *(const float4*)src;
        float4 f1 = *(const float4*)(src + 4);
        uint4 pk;
        pk.x = cvtpk(f0.x, f0.y);
        pk.y = cvtpk(f0.z, f0.w);
        pk.z = cvtpk(f1.x, f1.y);
        pk.w = cvtpk(f1.z, f1.w);
        *(uint4*)&Al[c * 512 + lane * 8] = pk;
      }
    } else {
      const ushort* A = (const ushort*)Ap;
#pragma unroll
      for (int i = 0; i < MF; ++i) {
        int c = wave * MF + i;
        load_lds16(A + (size_t)(bm + c * 8 + sl) * K + kt + sc8, &Al[c * 512]);
      }
    }
#pragma unroll
    for (int i = 0; i < NF; ++i) {
      int c = wave * NF + i;
      load_lds16(Bt + (size_t)(bn + c * 8 + sl) * K + kt + sc8, &Bl[c * 512]);
    }
    __syncthreads();
#pragma unroll
    for (int kk = 0; kk < 2; ++kk) {
      bf16x8 a[MF], b[NF];
#pragma unroll
      for (int m = 0; m < MF; ++m)
        a[m] = *(const bf16x8*)&Al[(wr * (BM / 2) + m * 16 + r0) * 64 + (((kk * 4 + kq) ^ (r0 & 7)) * 8)];
#pragma unroll
      for (int n = 0; n < NF; ++n)
        b[n] = *(const bf16x8*)&Bl[(wc * (BN / 2) + n * 16 + r0) * 64 + (((kk * 4 + kq) ^ (r0 & 7)) * 8)];
#pragma unroll
      for (int m = 0; m < MF; ++m)
#pragma unroll
        for (int n = 0; n < NF; ++n)
          acc[m][n] = __builtin_amdgcn_mfma_f32_16x16x32_bf16(a[m], b[n], acc[m][n], 0, 0, 0);
    }
    if (DOZERO) {
      int step = kt >> 6;   // 0..15
      if (step >= 3 && step <= 11 && (step & 1)) // steps 3,5,7,9,11 -> 5 tiles
        zero_tile(zwout, zid0 + ((step - 3) >> 1), tid);
    }
  }

#pragma unroll
  for (int m = 0; m < MF; ++m) {
#pragma unroll
    for (int n = 0; n < NF; ++n) {
      int col = bn + wc * (BN / 2) + n * 16 + r0;
      float bv = bias[col];
#pragma unroll
      for (int j = 0; j < 4; ++j) {
        int row = bm + wr * (BM / 2) + m * 16 + kq * 4 + j;
        float v = acc[m][n][j] + bv;
        if (BF16OUT) ((ushort*)Cp)[(size_t)row * N + col] = f2bf(v);
        else         ((float*)Cp)[(size_t)row * N + col] = v;
      }
    }
  }
}

__global__ __launch_bounds__(256) void gemm_qkv(const float* __restrict__ qa,
                                                const float* __restrict__ ka,
                                                const float* __restrict__ va,
                                                const ushort* __restrict__ WqT,
                                                const ushort* __restrict__ WkT,
                                                const ushort* __restrict__ WvT,
                                                const float* __restrict__ bq,
                                                const float* __restrict__ bk,
                                                const float* __restrict__ bv,
                                                ushort* __restrict__ Qo,
                                                ushort* __restrict__ Ko,
                                                ushort* __restrict__ Vo,
                                                float* __restrict__ wout) {
  const float* A; const ushort* Bt; const float* bias; ushort* C;
  switch (blockIdx.z) {
    case 0: A = qa; Bt = WqT; bias = bq; C = Qo; break;
    case 1: A = ka; Bt = WkT; bias = bk; C = Ko; break;
    default: A = va; Bt = WvT; bias = bv; C = Vo; break;
  }
  int bid = blockIdx.x + 64 * blockIdx.y + 512 * blockIdx.z;   // 0..1535
  gemm_body<1, 64, 128, 1, 1>(A, Bt, bias, C, blockIdx.x * 64, blockIdx.y * 128,
                              D_, D_, wout, bid * 5);
}

__global__ __launch_bounds__(256) void gemm_out(const ushort* __restrict__ A,
                                                const ushort* __restrict__ Bt,
                                                const float* __restrict__ bias,
                                                float* __restrict__ C) {
  gemm_body<0, 64, 64, 0, 0>(A, Bt, bias, C, blockIdx.x * 64, blockIdx.y * 64,
                             D_, D_, nullptr, 0);
}

// ---------------- fused attention, PAIRED q-tiles (qtA=15-p heavy, qtB=p light) ----
// grid 512: id&63 = (b,h) -> XCD-local K/V panel; p = id>>6 (heavy pairs first).
// Masked-region zeros are written by gemm_qkv (disjoint region) -> attn writes
// only the causal triangle (~150MB instead of ~284MB).
__global__ __launch_bounds__(256) void attn_fused(const ushort* __restrict__ Qb,
                                                  const ushort* __restrict__ Kb,
                                                  const ushort* __restrict__ Vb,
                                                  float* __restrict__ wout,
                                                  ushort* __restrict__ ctx) {
  const int id = blockIdx.x;
  const int bh = id & 63;
  const int b = bh >> 4, h = bh & 15;
  const int p = id >> 6;
  const int qtA = NT_ - 1 - p;   // 8..15
  const int qtB = p;             // 0..7
  const int tid = threadIdx.x, wave = tid >> 6, lane = tid & 63;
  const int r0 = lane & 15, kq = lane >> 4;
  const int sl = lane >> 3;
  const int sc8 = ((lane & 7) ^ sl) * 8;
  __shared__ ushort Kt[2][64 * 64];
  __shared__ ushort Vt[2][64 * 64];
  __shared__ ushort Wl[4][16 * 64];
  const size_t bh_off = ((size_t)(b * S_)) * D_ + (size_t)h * 64;
  float* wbase = wout + (size_t)bh * S_ * S_;
  const float KSC = 0.18033688011f;   // 0.125 * log2(e)

  const ushort* QgA = Qb + bh_off + (size_t)(qtA * 64 + wave * 16 + r0) * D_ + kq * 8;
  bf16x8 qa0A = *(const bf16x8*)QgA;
  bf16x8 qa1A = *(const bf16x8*)(QgA + 32);
  const ushort* QgB = Qb + bh_off + (size_t)(qtB * 64 + wave * 16 + r0) * D_ + kq * 8;
  bf16x8 qa0B = *(const bf16x8*)QgB;
  bf16x8 qa1B = *(const bf16x8*)(QgB + 32);
  const int qgA = qtA * 64 + wave * 16 + r0;
  const int qgB = qtB * 64 + wave * 16 + r0;

  auto stage_K = [&](int buf, int vb) {
    const ushort* Kg = Kb + bh_off + (size_t)(vb * 64) * D_;
#pragma unroll
    for (int i = 0; i < 2; ++i) {
      int c = wave * 2 + i;
      load_lds16(Kg + (size_t)(c * 8 + sl) * D_ + sc8, &Kt[buf][c * 512]);
    }
  };
  uint4 vr[2];
  auto vload = [&](int vb) {
    const ushort* Vg = Vb + bh_off + (size_t)(vb * 64) * D_;
    vr[0] = *(const uint4*)&Vg[(size_t)lane * D_ + (size_t)(wave * 2 + 0) * 8];
    vr[1] = *(const uint4*)&Vg[(size_t)lane * D_ + (size_t)(wave * 2 + 1) * 8];
  };
  auto vwrite = [&](int buf) {
#pragma unroll
    for (int it = 0; it < 2; ++it) {
      int seg = wave * 2 + it;
      ushort tmp[8];
      *(uint4*)tmp = vr[it];
#pragma unroll
      for (int e = 0; e < 8; ++e) Vt[buf][(seg * 8 + e) * 64 + (lane ^ (e << 3))] = tmp[e];
    }
  };

  f32x4 zero = {0.f, 0.f, 0.f, 0.f};

  // ================= phase 1: pass1(A) =================
  int cur = 0;
  stage_K(0, 0);
  float pA0 = 0.f, pA1 = 0.f, pA2 = 0.f, pA3 = 0.f;
  for (int vb = 0; vb <= qtA; ++vb) {
    asm volatile("s_waitcnt vmcnt(0)" ::: "memory");
    __builtin_amdgcn_s_barrier();
    if (vb < qtA) stage_K(cur ^ 1, vb + 1);
    const bool diag = (vb == qtA);
#pragma unroll
    for (int jt = 0; jt < 4; ++jt) {
      int krow = jt * 16 + r0;
      bf16x8 kb0 = *(const bf16x8*)&Kt[cur][krow * 64 + ((kq ^ (r0 & 7)) * 8)];
      bf16x8 kb1 = *(const bf16x8*)&Kt[cur][krow * 64 + (((4 + kq) ^ (r0 & 7)) * 8)];
      f32x4 sc = {0.f, 0.f, 0.f, 0.f};
      sc = __builtin_amdgcn_mfma_f32_16x16x32_bf16(kb0, qa0A, sc, 0, 0, 0);
      sc = __builtin_amdgcn_mfma_f32_16x16x32_bf16(kb1, qa1A, sc, 0, 0, 0);
      int k0 = vb * 64 + jt * 16 + kq * 4;
      pA0 += (diag && k0 + 0 > qgA) ? 0.f : exp2f(sc[0] * KSC);
      pA1 += (diag && k0 + 1 > qgA) ? 0.f : exp2f(sc[1] * KSC);
      pA2 += (diag && k0 + 2 > qgA) ? 0.f : exp2f(sc[2] * KSC);
      pA3 += (diag && k0 + 3 > qgA) ? 0.f : exp2f(sc[3] * KSC);
    }
    cur ^= 1;
  }
  float ssumA = (pA0 + pA1) + (pA2 + pA3);
  ssumA += __shfl_xor(ssumA, 16, 64);
  ssumA += __shfl_xor(ssumA, 32, 64);
  const float rsA = 1.f / ssumA;

  // ================= phase 2: pass2(A) fused with pass1(B) =================
  f32x4 caccA[4];
#pragma unroll
  for (int nt = 0; nt < 4; ++nt) caccA[nt] = zero;
  float pB0 = 0.f, pB1 = 0.f, pB2 = 0.f, pB3 = 0.f;

  __syncthreads();
  cur = 0;
  stage_K(0, 0);
  vload(0);
  vwrite(0);
  for (int vb = 0; vb <= qtA; ++vb) {
    if (vb == 0) asm volatile("s_waitcnt vmcnt(0) lgkmcnt(0)" ::: "memory");
    else         asm volatile("s_waitcnt vmcnt(4) lgkmcnt(0)" ::: "memory");
    __builtin_amdgcn_s_barrier();
    if (vb < qtA) { stage_K(cur ^ 1, vb + 1); vload(vb + 1); }
    const bool diagA = (vb == qtA);
    const bool doB = (vb <= qtB);
    const bool diagB = (vb == qtB);
#pragma unroll
    for (int jt = 0; jt < 4; ++jt) {
      int krow = jt * 16 + r0;
      bf16x8 kb0 = *(const bf16x8*)&Kt[cur][krow * 64 + ((kq ^ (r0 & 7)) * 8)];
      bf16x8 kb1 = *(const bf16x8*)&Kt[cur][krow * 64 + (((4 + kq) ^ (r0 & 7)) * 8)];
      int k0 = vb * 64 + jt * 16 + kq * 4;
      f32x4 sc = {0.f, 0.f, 0.f, 0.f};
      sc = __builtin_amdgcn_mfma_f32_16x16x32_bf16(kb0, qa0A, sc, 0, 0, 0);
      sc = __builtin_amdgcn_mfma_f32_16x16x32_bf16(kb1, qa1A, sc, 0, 0, 0);
      float e0 = (diagA && k0 + 0 > qgA) ? 0.f : exp2f(sc[0] * KSC);
      float e1 = (diagA && k0 + 1 > qgA) ? 0.f : exp2f(sc[1] * KSC);
      float e2 = (diagA && k0 + 2 > qgA) ? 0.f : exp2f(sc[2] * KSC);
      float e3 = (diagA && k0 + 3 > qgA) ? 0.f : exp2f(sc[3] * KSC);
      uint2 pk;
      pk.x = cvtpk(e0, e1);
      pk.y = cvtpk(e2, e3);
      int s = (4 * jt + kq) ^ ((r0 & 3) << 2);
      *(uint2*)&Wl[wave][r0 * 64 + s * 4] = pk;
      f32x4 o = {e0 * rsA, e1 * rsA, e2 * rsA, e3 * rsA};
      *(f32x4*)&wbase[(size_t)qgA * S_ + k0] = o;
      if (doB) {
        f32x4 sb = {0.f, 0.f, 0.f, 0.f};
        sb = __builtin_amdgcn_mfma_f32_16x16x32_bf16(kb0, qa0B, sb, 0, 0, 0);
        sb = __builtin_amdgcn_mfma_f32_16x16x32_bf16(kb1, qa1B, sb, 0, 0, 0);
        pB0 += (diagB && k0 + 0 > qgB) ? 0.f : exp2f(sb[0] * KSC);
        pB1 += (diagB && k0 + 1 > qgB) ? 0.f : exp2f(sb[1] * KSC);
        pB2 += (diagB && k0 + 2 > qgB) ? 0.f : exp2f(sb[2] * KSC);
        pB3 += (diagB && k0 + 3 > qgB) ? 0.f : exp2f(sb[3] * KSC);
      }
    }
#pragma unroll
    for (int ks = 0; ks < 2; ++ks) {
      int sB = (8 * ks + 2 * kq) ^ ((r0 & 3) << 2);
      bf16x8 af = *(const bf16x8*)&Wl[wave][r0 * 64 + sB * 4];
#pragma unroll
      for (int nt = 0; nt < 4; ++nt) {
        bf16x8 vf = *(const bf16x8*)&Vt[cur][(nt * 16 + r0) * 64 + (((ks * 4 + kq) ^ (r0 & 7)) * 8)];
        caccA[nt] = __builtin_amdgcn_mfma_f32_16x16x32_bf16(af, vf, caccA[nt], 0, 0, 0);
      }
    }
    if (vb < qtA) vwrite(cur ^ 1);
    cur ^= 1;
  }
  float ssumB = (pB0 + pB1) + (pB2 + pB3);
  ssumB += __shfl_xor(ssumB, 16, 64);
  ssumB += __shfl_xor(ssumB, 32, 64);
  const float rsB = 1.f / ssumB;

  // ---- A epilogue: ctx only (zeros handled by gemm_qkv)
  {
    float rsj[4];
#pragma unroll
    for (int j = 0; j < 4; ++j) rsj[j] = __shfl(rsA, kq * 4 + j, 64);
    ushort* cg = ctx + ((size_t)(b * S_ + qtA * 64 + wave * 16 + kq * 4)) * D_ + h * 64;
#pragma unroll
    for (int nt = 0; nt < 4; ++nt)
#pragma unroll
      for (int j = 0; j < 4; ++j)
        cg[(size_t)j * D_ + nt * 16 + r0] = f2bf(caccA[nt][j] * rsj[j]);
  }

  // ================= phase 3: pass2(B) =================
  f32x4 caccB[4];
#pragma unroll
  for (int nt = 0; nt < 4; ++nt) caccB[nt] = zero;
  __syncthreads();
  cur = 0;
  stage_K(0, 0);
  vload(0);
  vwrite(0);
  for (int vb = 0; vb <= qtB; ++vb) {
    if (vb == 0) asm volatile("s_waitcnt vmcnt(0) lgkmcnt(0)" ::: "memory");
    else         asm volatile("s_waitcnt vmcnt(4) lgkmcnt(0)" ::: "memory");
    __builtin_amdgcn_s_barrier();
    if (vb < qtB) { stage_K(cur ^ 1, vb + 1); vload(vb + 1); }
    const bool diag = (vb == qtB);
#pragma unroll
    for (int jt = 0; jt < 4; ++jt) {
      int krow = jt * 16 + r0;
      bf16x8 kb0 = *(const bf16x8*)&Kt[cur][krow * 64 + ((kq ^ (r0 & 7)) * 8)];
      bf16x8 kb1 = *(const bf16x8*)&Kt[cur][krow * 64 + (((4 + kq) ^ (r0 & 7)) * 8)];
      f32x4 sc = {0.f, 0.f, 0.f, 0.f};
      sc = __builtin_amdgcn_mfma_f32_16x16x32_bf16(kb0, qa0B, sc, 0, 0, 0);
      sc = __builtin_amdgcn_mfma_f32_16x16x32_bf16(kb1, qa1B, sc, 0, 0, 0);
      int k0 = vb * 64 + jt * 16 + kq * 4;
      float e0 = (diag && k0 + 0 > qgB) ? 0.f : exp2f(sc[0] * KSC);
      float e1 = (diag && k0 + 1 > qgB) ? 0.f : exp2f(sc[1] * KSC);
      float e2 = (diag && k0 + 2 > qgB) ? 0.f : exp2f(sc[2] * KSC);
      float e3 = (diag && k0 + 3 > qgB) ? 0.f : exp2f(sc[3] * KSC);
      uint2 pk;
      pk.x = cvtpk(e0, e1);
      pk.y = cvtpk(e2, e3);
      int s = (4 * jt + kq) ^ ((r0 & 3) << 2);
      *(uint2*)&Wl[wave][r0 * 64 + s * 4] = pk;
      f32x4 o = {e0 * rsB, e1 * rsB, e2 * rsB, e3 * rsB};
      *(f32x4*)&wbase[(size_t)qgB * S_ + k0] = o;
    }
#pragma unroll
    for (int ks = 0; ks < 2; ++ks) {
      int sB = (8 * ks + 2 * kq) ^ ((r0 & 3) << 2);
      bf16x8 af = *(const bf16x8*)&Wl[wave][r0 * 64 + sB * 4];
#pragma unroll
      for (int nt = 0; nt < 4; ++nt) {
        bf16x8 vf = *(const bf16x8*)&Vt[cur][(nt * 16 + r0) * 64 + (((ks * 4 + kq) ^ (r0 & 7)) * 8)];
        caccB[nt] = __builtin_amdgcn_mfma_f32_16x16x32_bf16(af, vf, caccB[nt], 0, 0, 0);
      }
    }
    if (vb < qtB) vwrite(cur ^ 1);
    cur ^= 1;
  }

  // ---- B epilogue: ctx only (zeros handled by gemm_qkv)
  {
    float rsj[4];
#pragma unroll
    for (int j = 0; j < 4; ++j) rsj[j] = __shfl(rsB, kq * 4 + j, 64);
    ushort* cg = ctx + ((size_t)(b * S_ + qtB * 64 + wave * 16 + kq * 4)) * D_ + h * 64;
#pragma unroll
    for (int nt = 0; nt < 4; ++nt)
#pragma unroll
      for (int j = 0; j < 4; ++j)
        cg[(size_t)j * D_ + nt * 16 + r0] = f2bf(caccB[nt][j] * rsj[j]);
  }
}

extern "C" void kernel_launch(void* const* d_in, const int* in_sizes, int n_in,
                              void* d_out, int out_size, void* d_ws, size_t ws_size,
                              hipStream_t stream) {
  const float* q    = (const float*)d_in[0];
  const float* k    = (const float*)d_in[1];
  const float* v    = (const float*)d_in[2];
  const float* Wq   = (const float*)d_in[4];
  const float* bq   = (const float*)d_in[5];
  const float* Wk   = (const float*)d_in[6];
  const float* bk   = (const float*)d_in[7];
  const float* Wv   = (const float*)d_in[8];
  const float* bv   = (const float*)d_in[9];
  const float* Wo   = (const float*)d_in[10];
  const float* bo   = (const float*)d_in[11];

  char* ws = (char*)d_ws;
  const size_t MB = 1024 * 1024;
  ushort* WqT    = (ushort*)(ws + 24 * MB);
  ushort* WkT    = (ushort*)(ws + 26 * MB);
  ushort* WvT    = (ushort*)(ws + 28 * MB);
  ushort* WoT    = (ushort*)(ws + 30 * MB);
  ushort* Q_bf   = (ushort*)(ws + 32 * MB);
  ushort* K_bf   = (ushort*)(ws + 40 * MB);
  ushort* V_bf   = (ushort*)(ws + 48 * MB);
  ushort* ctx_bf = (ushort*)(ws + 56 * MB);

  float* out  = (float*)d_out;
  float* wout = out + (size_t)M_ * D_;

  trW<<<dim3(32, 32, 4), 256, 0, stream>>>(Wq, Wk, Wv, Wo, WqT, WkT, WvT, WoT);
  gemm_qkv<<<dim3(M_ / 64, D_ / 128, 3), 256, 0, stream>>>(
      q, k, v, WqT, WkT, WvT, bq, bk, bv, Q_bf, K_bf, V_bf, wout);
  attn_fused<<<dim3(512), 256, 0, stream>>>(Q_bf, K_bf, V_bf, wout, ctx_bf);
  gemm_out<<<dim3(M_ / 64, D_ / 64), 256, 0, stream>>>(ctx_bf, WoT, bo, out);
}